// Round 1
// 519.723 us; speedup vs baseline: 1.1040x; 1.1040x over previous
//
#include <hip/hip_runtime.h>

typedef unsigned short u16;
typedef __bf16 bf16x8 __attribute__((ext_vector_type(8)));
typedef float f32x4 __attribute__((ext_vector_type(4)));

#define SCALE_QK 0.08838834764831845f
#define LOG2E 1.4426950408889634f
#define NEGBIG (-1e9f)

static __device__ __forceinline__ float bf2f(u16 u) {
  union { float f; unsigned int i; } x; x.i = ((unsigned int)u) << 16; return x.f;
}
static __device__ __forceinline__ u16 f2bf(float f) {
  union { float f; unsigned int i; } x; x.f = f;
  return (u16)((x.i + 0x7fffu + ((x.i >> 16) & 1u)) >> 16);
}
static __device__ __forceinline__ void async16(const u16* g, u16* s) {
  __builtin_amdgcn_global_load_lds(
      (const __attribute__((address_space(1))) void*)g,
      (__attribute__((address_space(3))) void*)s, 16, 0, 0);
}

// -------- dtype probe: flags[t]=1 if tensor t is f32-stored, 0 if bf16 ------
__global__ __launch_bounds__(64) void detect_dtype(
    const void* p0, const void* p1, const void* p2, const void* p3,
    const void* p4, const void* p5, int* flags) {
  const void* ps[6] = {p0, p1, p2, p3, p4, p5};
  const u16* p = (const u16*)ps[blockIdx.x];
  int lane = threadIdx.x;
  u16 u = p[2 * lane];
  int e = (u >> 7) & 0xFF;
  int plaus = (e >= 112 && e <= 143) ? 1 : 0;
  unsigned long long m = __ballot(plaus);
  if (lane == 0) {
    flags[blockIdx.x] = (__popcll(m) < 32) ? 1 : 0;
    if (blockIdx.x == 0) flags[6] = 0;  // forced-bf16 flag (internal GEMM out)
  }
}

// -------- transpose: src (K x N, f32 or bf16) -> dst bf16 (N x K) -----------
__global__ __launch_bounds__(256) void transpose_to_bf16(
    const void* __restrict__ src, u16* __restrict__ dst, int N, int K,
    const int* __restrict__ flag) {
  const int LT = 74;
  __shared__ u16 t[64 * LT];
  const int tid = threadIdx.x;
  const int n0 = blockIdx.x * 64, k0 = blockIdx.y * 64;
  const int f32in = *flag;
  for (int c = tid; c < 512; c += 256) {
    int r = c >> 3, ch = (c & 7) * 8;
    u16* tp = t + r * LT + ch;
    if (f32in) {
      const float* p = (const float*)src + (size_t)(k0 + r) * N + n0 + ch;
      float4 v0 = *(const float4*)p;
      float4 v1 = *(const float4*)(p + 4);
      tp[0] = f2bf(v0.x); tp[1] = f2bf(v0.y); tp[2] = f2bf(v0.z); tp[3] = f2bf(v0.w);
      tp[4] = f2bf(v1.x); tp[5] = f2bf(v1.y); tp[6] = f2bf(v1.z); tp[7] = f2bf(v1.w);
    } else {
      uint4 v = *(const uint4*)((const u16*)src + (size_t)(k0 + r) * N + n0 + ch);
      const u16* pv = (const u16*)&v;
#pragma unroll
      for (int e = 0; e < 8; ++e) tp[e] = pv[e];
    }
  }
  __syncthreads();
  for (int c = tid; c < 512; c += 256) {
    int rr = c >> 3, cc = (c & 7) * 8;
    u16 tmp[8];
#pragma unroll
    for (int e = 0; e < 8; ++e) tmp[e] = t[(cc + e) * LT + rr];
    *(uint4*)(dst + (size_t)(n0 + rr) * K + k0 + cc) = *(const uint4*)tmp;
  }
}

// -------- flat cast to bf16 -------------------------------------------------
__global__ __launch_bounds__(256) void cast_to_bf16(
    const void* __restrict__ src, u16* __restrict__ dst, const int* __restrict__ flag) {
  int i = (blockIdx.x * 256 + threadIdx.x) * 8;
  if (*flag) {
    float4 v0 = *(const float4*)((const float*)src + i);
    float4 v1 = *(const float4*)((const float*)src + i + 4);
    u16 tmp[8] = {f2bf(v0.x), f2bf(v0.y), f2bf(v0.z), f2bf(v0.w),
                  f2bf(v1.x), f2bf(v1.y), f2bf(v1.z), f2bf(v1.w)};
    *(uint4*)(dst + i) = *(const uint4*)tmp;
  } else {
    *(uint4*)(dst + i) = *(const uint4*)((const u16*)src + i);
  }
}

// -------- GEMM: C(MxN) = A(MxK)*Bt(NxK)^T; A/B bf16; C f32 or bf16 per flag -
__global__ __launch_bounds__(256, 2) void gemm_bt(
    const u16* __restrict__ A, const u16* __restrict__ Bt, void* __restrict__ C,
    int K, int lda, int ldb, int ldc, const int* __restrict__ oflag) {
  __shared__ u16 sA[128 * 32];
  __shared__ u16 sB[128 * 32];
  const int tid = threadIdx.x;
  const int wave = tid >> 6, lane = tid & 63;
  const int quad = lane >> 4, l16 = lane & 15;
  const int wr = wave >> 1, wc = wave & 1;
  const int bm = blockIdx.y << 7, bn = blockIdx.x << 7;
  const int f32out = *oflag;

  f32x4 acc[4][4] = {};

  const int c0 = tid, c1 = tid + 256;
  const int r0 = c0 >> 2, h0 = (c0 & 3) * 8;
  const int r1 = c1 >> 2, h1 = (c1 & 3) * 8;
  const u16* a0 = A + (size_t)(bm + r0) * lda + h0;
  const u16* a1 = A + (size_t)(bm + r1) * lda + h1;
  const u16* b0 = Bt + (size_t)(bn + r0) * ldb + h0;
  const u16* b1 = Bt + (size_t)(bn + r1) * ldb + h1;

  for (int k0 = 0; k0 < K; k0 += 32) {
    async16(a0 + k0, sA + c0 * 8);
    async16(a1 + k0, sA + c1 * 8);
    async16(b0 + k0, sB + c0 * 8);
    async16(b1 + k0, sB + c1 * 8);
    __syncthreads();
    bf16x8 af[4], bv[4];
#pragma unroll
    for (int i = 0; i < 4; ++i)
      af[i] = *(const bf16x8*)(sA + (wr * 64 + i * 16 + l16) * 32 + quad * 8);
#pragma unroll
    for (int j = 0; j < 4; ++j)
      bv[j] = *(const bf16x8*)(sB + (wc * 64 + j * 16 + l16) * 32 + quad * 8);
#pragma unroll
    for (int i = 0; i < 4; ++i)
#pragma unroll
      for (int j = 0; j < 4; ++j)
        acc[i][j] =
            __builtin_amdgcn_mfma_f32_16x16x32_bf16(af[i], bv[j], acc[i][j], 0, 0, 0);
    __syncthreads();
  }
#pragma unroll
  for (int i = 0; i < 4; ++i) {
    int row = bm + wr * 64 + i * 16 + quad * 4;
#pragma unroll
    for (int j = 0; j < 4; ++j) {
      int col = bn + wc * 64 + j * 16 + l16;
#pragma unroll
      for (int r = 0; r < 4; ++r) {
        size_t idx = (size_t)(row + r) * ldc + col;
        if (f32out) ((float*)C)[idx] = acc[i][j][r];
        else ((u16*)C)[idx] = f2bf(acc[i][j][r]);
      }
    }
  }
}

// -------- RoPE in place on Q (slots 0..31) and K (slots 32..39) -------------
__global__ __launch_bounds__(256) void rope_kernel(
    u16* __restrict__ QKV, const void* __restrict__ cosb,
    const void* __restrict__ sinb, const int* __restrict__ flag) {
  int idx = blockIdx.x * 256 + threadIdx.x;  // total 2048*40*64
  int d = idx & 63;
  int rest = idx >> 6;
  int slot = rest % 40;
  int tok = rest / 40;
  int col = (slot < 32) ? (slot * 128 + d) : (4096 + (slot - 32) * 128 + d);
  size_t base = (size_t)tok * 6144 + col;
  float x1 = bf2f(QKV[base]);
  float x2 = bf2f(QKV[base + 64]);
  size_t cb = (size_t)tok * 128 + d;
  float c1, s1, c2, s2;
  if (*flag) {
    c1 = ((const float*)cosb)[cb]; s1 = ((const float*)sinb)[cb];
    c2 = ((const float*)cosb)[cb + 64]; s2 = ((const float*)sinb)[cb + 64];
  } else {
    c1 = bf2f(((const u16*)cosb)[cb]); s1 = bf2f(((const u16*)sinb)[cb]);
    c2 = bf2f(((const u16*)cosb)[cb + 64]); s2 = bf2f(((const u16*)sinb)[cb + 64]);
  }
  QKV[base] = f2bf(x1 * c1 - x2 * s1);
  QKV[base + 64] = f2bf(x2 * c2 + x1 * s2);
}

// -------- flash attention: BQ=BKV=64, causal, GQA 4:1 -----------------------
// LDS 42 KB. Q frags in regs (pre-scaled, log2 domain).
// sV XOR-swizzled: elem(d,kv) at d*64 + (((kv>>3)^((d>>3)&7))<<3) + (kv&7):
// transpose-store <=2-way conflicts (vs 16-way with padded linear layout).
// K/V for next kb prefetched into regs during compute.
//
// LOAD BALANCE (this round): causal work per q-tile qt is (qt+1) KV tiles,
// a 1:16 spread. Each block now owns the PAIR {qt=p, qt=15-p}: every block
// does exactly 17 KV-tile iterations -> 512 uniform blocks (2/CU, all
// resident from t=0, no backfill tail). The end-of-KV-loop __syncthreads
// already orders pass-0 LDS reads against pass-1's first commit.
__global__ __launch_bounds__(256, 3) void attn_kernel(
    const u16* __restrict__ QKV, u16* __restrict__ O) {
  const int LK = 136;  // sK row stride (bank-spread for b128 reads)
  const int LP = 72;   // sP row stride
  __shared__ u16 sK[64 * LK];
  __shared__ u16 sV[128 * 64];
  __shared__ u16 sP[64 * LP];
  const int tid = threadIdx.x, wave = tid >> 6, lane = tid & 63;
  const int quad = lane >> 4, l16 = lane & 15;
  const int pp = blockIdx.x, h = blockIdx.y, b = blockIdx.z;
  const int kvh = h >> 2;
  const size_t tb = (size_t)b * 1024 * 6144;
  const u16* Qg = QKV + tb + (size_t)h * 128;
  const u16* Kg = QKV + tb + 4096 + (size_t)kvh * 128;
  const u16* Vg = QKV + tb + 5120 + (size_t)kvh * 128;

#pragma unroll 1
  for (int pass = 0; pass < 2; ++pass) {
    const int qt = pass ? (15 - pp) : pp;

    // Q a-frags (loop-invariant), folded scale * log2e -> exp2 softmax domain
    bf16x8 qa[4];
    {
      const int qrow = qt * 64 + wave * 16 + l16;
#pragma unroll
      for (int kc = 0; kc < 4; ++kc) {
        bf16x8 v = *(const bf16x8*)(Qg + (size_t)qrow * 6144 + kc * 32 + quad * 8);
#pragma unroll
        for (int e = 0; e < 8; ++e) v[e] = (__bf16)((float)v[e] * (SCALE_QK * LOG2E));
        qa[kc] = v;
      }
    }

    uint4 kreg[4], vreg[4];
#pragma unroll
    for (int i = 0; i < 4; ++i) {
      int c = i * 256 + tid, row = c >> 4, ch = (c & 15) * 8;
      kreg[i] = *(const uint4*)(Kg + (size_t)row * 6144 + ch);
      vreg[i] = *(const uint4*)(Vg + (size_t)row * 6144 + ch);
    }

    float m_run[4], l_run[4];
    f32x4 oacc[8] = {};
#pragma unroll
    for (int r = 0; r < 4; ++r) { m_run[r] = -INFINITY; l_run[r] = 0.f; }

    const int nkb = qt + 1;
    for (int kb = 0; kb < nkb; ++kb) {
      // commit prefetched tile to LDS
#pragma unroll
      for (int i = 0; i < 4; ++i) {
        int c = i * 256 + tid, row = c >> 4, ch = (c & 15) * 8;
        *(uint4*)(sK + row * LK + ch) = kreg[i];
        const u16* pw = (const u16*)&vreg[i];
#pragma unroll
        for (int e = 0; e < 8; ++e) {
          int d = ch + e;
          sV[d * 64 + ((((row >> 3) ^ (d >> 3)) & 7) << 3) + (row & 7)] = pw[e];
        }
      }
      __syncthreads();
      if (kb + 1 < nkb) {
#pragma unroll
        for (int i = 0; i < 4; ++i) {
          int c = i * 256 + tid, row = c >> 4, ch = (c & 15) * 8;
          kreg[i] = *(const uint4*)(Kg + (size_t)((kb + 1) * 64 + row) * 6144 + ch);
          vreg[i] = *(const uint4*)(Vg + (size_t)((kb + 1) * 64 + row) * 6144 + ch);
        }
      }

      f32x4 sc[4] = {};
#pragma unroll
      for (int kc = 0; kc < 4; ++kc)
#pragma unroll
        for (int j = 0; j < 4; ++j) {
          bf16x8 bb = *(const bf16x8*)(sK + (j * 16 + l16) * LK + kc * 32 + quad * 8);
          sc[j] = __builtin_amdgcn_mfma_f32_16x16x32_bf16(qa[kc], bb, sc[j], 0, 0, 0);
        }

      const int rowg = qt * 64 + wave * 16 + quad * 4;
      const int colg = kb * 64 + l16;
      float mloc[4] = {NEGBIG, NEGBIG, NEGBIG, NEGBIG};
#pragma unroll
      for (int j = 0; j < 4; ++j)
#pragma unroll
        for (int r = 0; r < 4; ++r) {
          float v = sc[j][r];
          if (colg + j * 16 > rowg + r) v = NEGBIG;
          sc[j][r] = v;
          mloc[r] = fmaxf(mloc[r], v);
        }
#pragma unroll
      for (int off = 1; off < 16; off <<= 1)
#pragma unroll
        for (int r = 0; r < 4; ++r)
          mloc[r] = fmaxf(mloc[r], __shfl_xor(mloc[r], off, 64));

      float alpha[4], lad[4];
#pragma unroll
      for (int r = 0; r < 4; ++r) {
        float mn = fmaxf(m_run[r], mloc[r]);
        alpha[r] = exp2f(m_run[r] - mn);
        m_run[r] = mn;
        lad[r] = 0.f;
      }
#pragma unroll
      for (int j = 0; j < 4; ++j)
#pragma unroll
        for (int r = 0; r < 4; ++r) {
          float p = exp2f(sc[j][r] - m_run[r]);
          sc[j][r] = p;
          lad[r] += p;
        }
#pragma unroll
      for (int off = 1; off < 16; off <<= 1)
#pragma unroll
        for (int r = 0; r < 4; ++r) lad[r] += __shfl_xor(lad[r], off, 64);
#pragma unroll
      for (int r = 0; r < 4; ++r) l_run[r] = l_run[r] * alpha[r] + lad[r];
#pragma unroll
      for (int dt = 0; dt < 8; ++dt)
#pragma unroll
        for (int r = 0; r < 4; ++r) oacc[dt][r] *= alpha[r];

#pragma unroll
      for (int j = 0; j < 4; ++j)
#pragma unroll
        for (int r = 0; r < 4; ++r)
          sP[(wave * 16 + quad * 4 + r) * LP + j * 16 + l16] = f2bf(sc[j][r]);
      __asm__ __volatile__("s_waitcnt lgkmcnt(0)" ::: "memory");  // sP intra-wave

#pragma unroll
      for (int kc = 0; kc < 2; ++kc) {
        bf16x8 a = *(const bf16x8*)(sP + (wave * 16 + l16) * LP + kc * 32 + quad * 8);
#pragma unroll
        for (int dt = 0; dt < 8; ++dt) {
          int d = dt * 16 + l16;
          int chk = ((kc * 4 + quad) ^ (d >> 3)) & 7;
          bf16x8 bb = *(const bf16x8*)(sV + d * 64 + chk * 8);
          oacc[dt] = __builtin_amdgcn_mfma_f32_16x16x32_bf16(a, bb, oacc[dt], 0, 0, 0);
        }
      }
      __syncthreads();
    }

    const int srow = qt * 64 + wave * 16 + quad * 4;
#pragma unroll
    for (int dt = 0; dt < 8; ++dt)
#pragma unroll
      for (int r = 0; r < 4; ++r) {
        float val = oacc[dt][r] / l_run[r];
        O[((size_t)b * 1024 + srow + r) * 4096 + h * 128 + dt * 16 + l16] = f2bf(val);
      }
  }
}

// ---------------------------------------------------------------------------
extern "C" void kernel_launch(void* const* d_in, const int* in_sizes, int n_in,
                              void* d_out, int out_size, void* d_ws, size_t ws_size,
                              hipStream_t stream) {
  (void)in_sizes; (void)n_in; (void)out_size; (void)ws_size;
  const void* hidden = d_in[0];  // (2048, 4096)
  const void* cosb   = d_in[1];  // (2, 1024, 128)
  const void* sinb   = d_in[2];
  // d_in[3] = attention_mask (causal; reproduced analytically)
  const void* Wq = d_in[4];  // (4096, 4096)
  const void* Wk = d_in[5];  // (4096, 1024)
  const void* Wv = d_in[6];  // (4096, 1024)
  const void* Wo = d_in[7];  // (4096, 4096)

  u16* ws = (u16*)d_ws;
  u16* Wqkvt = ws;                        // bf16 (6144,4096); reused as Wot
  u16* Wot   = ws;
  u16* Xb    = ws + (size_t)25165824;     // bf16 (2048,4096); reused as attnb
  u16* attnb = Xb;
  u16* QKV   = ws + (size_t)33554432;     // bf16 (2048,6144)
  int* flags = (int*)(ws + (size_t)46137344);  // 8 ints

  // flags: 0=hidden 1=cos 2=Wq 3=Wk 4=Wv 5=Wo, 6=always-0 (bf16 out)
  detect_dtype<<<6, 64, 0, stream>>>(hidden, cosb, Wq, Wk, Wv, Wo, flags);

  transpose_to_bf16<<<dim3(64, 64), 256, 0, stream>>>(Wq, Wqkvt, 4096, 4096, flags + 2);
  transpose_to_bf16<<<dim3(16, 64), 256, 0, stream>>>(Wk, Wqkvt + (size_t)4096 * 4096, 1024, 4096, flags + 3);
  transpose_to_bf16<<<dim3(16, 64), 256, 0, stream>>>(Wv, Wqkvt + (size_t)5120 * 4096, 1024, 4096, flags + 4);
  cast_to_bf16<<<4096, 256, 0, stream>>>(hidden, Xb, flags + 0);

  gemm_bt<<<dim3(48, 16), 256, 0, stream>>>(Xb, Wqkvt, QKV, 4096, 4096, 4096, 6144, flags + 6);
  rope_kernel<<<20480, 256, 0, stream>>>(QKV, cosb, sinb, flags + 1);

  // Wqkvt consumed by gemm1 -> overwrite with Wo^T (stream-ordered)
  transpose_to_bf16<<<dim3(64, 64), 256, 0, stream>>>(Wo, Wot, 4096, 4096, flags + 5);

  // paired q-tiles {p, 15-p}: 512 uniform blocks of 17 KV-tile iterations
  attn_kernel<<<dim3(8, 32, 2), 256, 0, stream>>>(QKV, attnb);
  // out dtype follows hidden's storage dtype
  gemm_bt<<<dim3(32, 16), 256, 0, stream>>>(attnb, Wot, d_out, 4096, 4096, 4096, 4096, flags + 0);
}

// Round 2
// 502.701 us; speedup vs baseline: 1.1413x; 1.0339x over previous
//
#include <hip/hip_runtime.h>

typedef unsigned short u16;
typedef __bf16 bf16x8 __attribute__((ext_vector_type(8)));
typedef float f32x4 __attribute__((ext_vector_type(4)));

#define SCALE_QK 0.08838834764831845f
#define LOG2E 1.4426950408889634f
#define NEGBIG (-1e9f)

static __device__ __forceinline__ float bf2f(u16 u) {
  union { float f; unsigned int i; } x; x.i = ((unsigned int)u) << 16; return x.f;
}
static __device__ __forceinline__ u16 f2bf(float f) {
  union { float f; unsigned int i; } x; x.f = f;
  return (u16)((x.i + 0x7fffu + ((x.i >> 16) & 1u)) >> 16);
}
static __device__ __forceinline__ void async16(const u16* g, u16* s) {
  __builtin_amdgcn_global_load_lds(
      (const __attribute__((address_space(1))) void*)g,
      (__attribute__((address_space(3))) void*)s, 16, 0, 0);
}

// -------- dtype probe: flags[t]=1 if tensor t is f32-stored, 0 if bf16 ------
__global__ __launch_bounds__(64) void detect_dtype(
    const void* p0, const void* p1, const void* p2, const void* p3,
    const void* p4, const void* p5, int* flags) {
  const void* ps[6] = {p0, p1, p2, p3, p4, p5};
  const u16* p = (const u16*)ps[blockIdx.x];
  int lane = threadIdx.x;
  u16 u = p[2 * lane];
  int e = (u >> 7) & 0xFF;
  int plaus = (e >= 112 && e <= 143) ? 1 : 0;
  unsigned long long m = __ballot(plaus);
  if (lane == 0) {
    flags[blockIdx.x] = (__popcll(m) < 32) ? 1 : 0;
    if (blockIdx.x == 0) flags[6] = 0;  // forced-bf16 flag (internal GEMM out)
  }
}

// -------- shared transpose body: src (K x N) tile -> dst bf16 (N x K) -------
static __device__ __forceinline__ void transpose_body(
    const void* __restrict__ src, u16* __restrict__ dst, int N, int K,
    int n0, int k0, int f32in, u16* t) {
  const int LT = 74;
  const int tid = threadIdx.x;
  for (int c = tid; c < 512; c += 256) {
    int r = c >> 3, ch = (c & 7) * 8;
    u16* tp = t + r * LT + ch;
    if (f32in) {
      const float* p = (const float*)src + (size_t)(k0 + r) * N + n0 + ch;
      float4 v0 = *(const float4*)p;
      float4 v1 = *(const float4*)(p + 4);
      tp[0] = f2bf(v0.x); tp[1] = f2bf(v0.y); tp[2] = f2bf(v0.z); tp[3] = f2bf(v0.w);
      tp[4] = f2bf(v1.x); tp[5] = f2bf(v1.y); tp[6] = f2bf(v1.z); tp[7] = f2bf(v1.w);
    } else {
      uint4 v = *(const uint4*)((const u16*)src + (size_t)(k0 + r) * N + n0 + ch);
      const u16* pv = (const u16*)&v;
#pragma unroll
      for (int e = 0; e < 8; ++e) tp[e] = pv[e];
    }
  }
  __syncthreads();
  for (int c = tid; c < 512; c += 256) {
    int rr = c >> 3, cc = (c & 7) * 8;
    u16 tmp[8];
#pragma unroll
    for (int e = 0; e < 8; ++e) tmp[e] = t[(cc + e) * LT + rr];
    *(uint4*)(dst + (size_t)(n0 + rr) * K + k0 + cc) = *(const uint4*)tmp;
  }
}

// -------- transpose: generic single-tensor version (used for Wo) ------------
__global__ __launch_bounds__(256) void transpose_to_bf16(
    const void* __restrict__ src, u16* __restrict__ dst, int N, int K,
    const int* __restrict__ flag) {
  __shared__ u16 t[64 * 74];
  transpose_body(src, dst, N, K, blockIdx.x * 64, blockIdx.y * 64, *flag, t);
}

// -------- fused transpose of Wq/Wk/Wv into Wqkvt (one launch) ---------------
// blockIdx.x: 0..63 -> Wq tiles; 64..79 -> Wk; 80..95 -> Wv
__global__ __launch_bounds__(256) void transpose_qkv(
    const void* __restrict__ Wq, const void* __restrict__ Wk,
    const void* __restrict__ Wv, u16* __restrict__ dst,
    const int* __restrict__ flags) {
  __shared__ u16 t[64 * 74];
  int bx = blockIdx.x;
  const void* src; u16* d; int N; int f32in; int nx;
  if (bx < 64)      { src = Wq; d = dst;                         N = 4096; f32in = flags[2]; nx = bx; }
  else if (bx < 80) { src = Wk; d = dst + (size_t)4096 * 4096;   N = 1024; f32in = flags[3]; nx = bx - 64; }
  else              { src = Wv; d = dst + (size_t)5120 * 4096;   N = 1024; f32in = flags[4]; nx = bx - 80; }
  transpose_body(src, d, N, 4096, nx * 64, blockIdx.y * 64, f32in, t);
}

// -------- flat cast to bf16 -------------------------------------------------
__global__ __launch_bounds__(256) void cast_to_bf16(
    const void* __restrict__ src, u16* __restrict__ dst, const int* __restrict__ flag) {
  int i = (blockIdx.x * 256 + threadIdx.x) * 8;
  if (*flag) {
    float4 v0 = *(const float4*)((const float*)src + i);
    float4 v1 = *(const float4*)((const float*)src + i + 4);
    u16 tmp[8] = {f2bf(v0.x), f2bf(v0.y), f2bf(v0.z), f2bf(v0.w),
                  f2bf(v1.x), f2bf(v1.y), f2bf(v1.z), f2bf(v1.w)};
    *(uint4*)(dst + i) = *(const uint4*)tmp;
  } else {
    *(uint4*)(dst + i) = *(const uint4*)((const u16*)src + i);
  }
}

// -------- GEMM: C(MxN) = A(MxK)*Bt(NxK)^T; A/B bf16; C f32 or bf16 per flag -
__global__ __launch_bounds__(256, 2) void gemm_bt(
    const u16* __restrict__ A, const u16* __restrict__ Bt, void* __restrict__ C,
    int K, int lda, int ldb, int ldc, const int* __restrict__ oflag) {
  __shared__ u16 sA[128 * 32];
  __shared__ u16 sB[128 * 32];
  const int tid = threadIdx.x;
  const int wave = tid >> 6, lane = tid & 63;
  const int quad = lane >> 4, l16 = lane & 15;
  const int wr = wave >> 1, wc = wave & 1;
  const int bm = blockIdx.y << 7, bn = blockIdx.x << 7;
  const int f32out = *oflag;

  f32x4 acc[4][4] = {};

  const int c0 = tid, c1 = tid + 256;
  const int r0 = c0 >> 2, h0 = (c0 & 3) * 8;
  const int r1 = c1 >> 2, h1 = (c1 & 3) * 8;
  const u16* a0 = A + (size_t)(bm + r0) * lda + h0;
  const u16* a1 = A + (size_t)(bm + r1) * lda + h1;
  const u16* b0 = Bt + (size_t)(bn + r0) * ldb + h0;
  const u16* b1 = Bt + (size_t)(bn + r1) * ldb + h1;

  for (int k0 = 0; k0 < K; k0 += 32) {
    async16(a0 + k0, sA + c0 * 8);
    async16(a1 + k0, sA + c1 * 8);
    async16(b0 + k0, sB + c0 * 8);
    async16(b1 + k0, sB + c1 * 8);
    __syncthreads();
    bf16x8 af[4], bv[4];
#pragma unroll
    for (int i = 0; i < 4; ++i)
      af[i] = *(const bf16x8*)(sA + (wr * 64 + i * 16 + l16) * 32 + quad * 8);
#pragma unroll
    for (int j = 0; j < 4; ++j)
      bv[j] = *(const bf16x8*)(sB + (wc * 64 + j * 16 + l16) * 32 + quad * 8);
#pragma unroll
    for (int i = 0; i < 4; ++i)
#pragma unroll
      for (int j = 0; j < 4; ++j)
        acc[i][j] =
            __builtin_amdgcn_mfma_f32_16x16x32_bf16(af[i], bv[j], acc[i][j], 0, 0, 0);
    __syncthreads();
  }
#pragma unroll
  for (int i = 0; i < 4; ++i) {
    int row = bm + wr * 64 + i * 16 + quad * 4;
#pragma unroll
    for (int j = 0; j < 4; ++j) {
      int col = bn + wc * 64 + j * 16 + l16;
#pragma unroll
      for (int r = 0; r < 4; ++r) {
        size_t idx = (size_t)(row + r) * ldc + col;
        if (f32out) ((float*)C)[idx] = acc[i][j][r];
        else ((u16*)C)[idx] = f2bf(acc[i][j][r]);
      }
    }
  }
}

// -------- RoPE in place, vectorized x8: Q (slots 0..31), K (slots 32..39) ---
__global__ __launch_bounds__(256) void rope_kernel(
    u16* __restrict__ QKV, const void* __restrict__ cosb,
    const void* __restrict__ sinb, const int* __restrict__ flag) {
  int idx = blockIdx.x * 256 + threadIdx.x;  // (tok*40 + slot)*8 + d-octet
  int d8 = (idx & 7) * 8;
  int rest = idx >> 3;
  int slot = rest % 40;
  int tok = rest / 40;
  int col = (slot < 32) ? (slot * 128 + d8) : (4096 + (slot - 32) * 128 + d8);
  size_t base = (size_t)tok * 6144 + col;
  uint4 va = *(const uint4*)(QKV + base);        // x1: d8..d8+7
  uint4 vb = *(const uint4*)(QKV + base + 64);   // x2: d8+64..d8+71
  const u16* pa = (const u16*)&va;
  const u16* pb = (const u16*)&vb;
  size_t cb = (size_t)tok * 128 + d8;
  float c1[8], s1[8], c2[8], s2[8];
  if (*flag) {
    const float* cp = (const float*)cosb + cb;
    const float* sp = (const float*)sinb + cb;
    float4 t0 = *(const float4*)cp,        t1 = *(const float4*)(cp + 4);
    float4 t2 = *(const float4*)(cp + 64), t3 = *(const float4*)(cp + 68);
    float4 u0 = *(const float4*)sp,        u1 = *(const float4*)(sp + 4);
    float4 u2 = *(const float4*)(sp + 64), u3 = *(const float4*)(sp + 68);
    const float* tf = (const float*)&t0;  // t0,t1 contiguous? not guaranteed; copy explicitly
    (void)tf;
    c1[0]=t0.x;c1[1]=t0.y;c1[2]=t0.z;c1[3]=t0.w;c1[4]=t1.x;c1[5]=t1.y;c1[6]=t1.z;c1[7]=t1.w;
    c2[0]=t2.x;c2[1]=t2.y;c2[2]=t2.z;c2[3]=t2.w;c2[4]=t3.x;c2[5]=t3.y;c2[6]=t3.z;c2[7]=t3.w;
    s1[0]=u0.x;s1[1]=u0.y;s1[2]=u0.z;s1[3]=u0.w;s1[4]=u1.x;s1[5]=u1.y;s1[6]=u1.z;s1[7]=u1.w;
    s2[0]=u2.x;s2[1]=u2.y;s2[2]=u2.z;s2[3]=u2.w;s2[4]=u3.x;s2[5]=u3.y;s2[6]=u3.z;s2[7]=u3.w;
  } else {
    const u16* cp = (const u16*)cosb + cb;
    const u16* sp = (const u16*)sinb + cb;
    uint4 t0 = *(const uint4*)cp, t1 = *(const uint4*)(cp + 64);
    uint4 u0 = *(const uint4*)sp, u1 = *(const uint4*)(sp + 64);
    const u16* q0 = (const u16*)&t0; const u16* q1 = (const u16*)&t1;
    const u16* r0 = (const u16*)&u0; const u16* r1 = (const u16*)&u1;
#pragma unroll
    for (int e = 0; e < 8; ++e) {
      c1[e] = bf2f(q0[e]); c2[e] = bf2f(q1[e]);
      s1[e] = bf2f(r0[e]); s2[e] = bf2f(r1[e]);
    }
  }
  u16 o1[8], o2[8];
#pragma unroll
  for (int e = 0; e < 8; ++e) {
    float x1 = bf2f(pa[e]), x2 = bf2f(pb[e]);
    o1[e] = f2bf(x1 * c1[e] - x2 * s1[e]);
    o2[e] = f2bf(x2 * c2[e] + x1 * s2[e]);
  }
  *(uint4*)(QKV + base) = *(const uint4*)o1;
  *(uint4*)(QKV + base + 64) = *(const uint4*)o2;
}

// -------- flash attention: BQ=BKV=64, causal, GQA 4:1 -----------------------
// Swapped QK^T (mfma(K,Q) -> S^T): each lane owns ONE q-row (q = l16), so the
// softmax row-reduce is a 15-op local chain + shfl_xor(16,32) instead of two
// 4-stage x 4-row trees (32 -> 4 cross-lane ops). alpha/l for the oacc rows
// (q = quad*4+r) fetched via 4 bpermutes. Defer-max (THR=8, log2 domain)
// skips the O-rescale when no row's max grew. P goes through sP transposed
// (same full tile, same b128 A-frag read as before). sV XOR-swizzled
// transpose-store; K/V next-tile prefetch in regs. Paired q-tiles {p,15-p}
// -> 512 uniform blocks of 17 KV iters.
__global__ __launch_bounds__(256, 3) void attn_kernel(
    const u16* __restrict__ QKV, u16* __restrict__ O) {
  const int LK = 136;  // sK row stride (bank-spread for b128 reads)
  const int LP = 72;   // sP row stride
  __shared__ u16 sK[64 * LK];
  __shared__ u16 sV[128 * 64];
  __shared__ u16 sP[64 * LP];
  const int tid = threadIdx.x, wave = tid >> 6, lane = tid & 63;
  const int quad = lane >> 4, l16 = lane & 15;
  const int pp = blockIdx.x, h = blockIdx.y, b = blockIdx.z;
  const int kvh = h >> 2;
  const size_t tb = (size_t)b * 1024 * 6144;
  const u16* Qg = QKV + tb + (size_t)h * 128;
  const u16* Kg = QKV + tb + 4096 + (size_t)kvh * 128;
  const u16* Vg = QKV + tb + 5120 + (size_t)kvh * 128;

#pragma unroll 1
  for (int pass = 0; pass < 2; ++pass) {
    const int qt = pass ? (15 - pp) : pp;

    // Q frags (loop-invariant), folded scale * log2e -> exp2 softmax domain
    bf16x8 qa[4];
    {
      const int qrow = qt * 64 + wave * 16 + l16;
#pragma unroll
      for (int kc = 0; kc < 4; ++kc) {
        bf16x8 v = *(const bf16x8*)(Qg + (size_t)qrow * 6144 + kc * 32 + quad * 8);
#pragma unroll
        for (int e = 0; e < 8; ++e) v[e] = (__bf16)((float)v[e] * (SCALE_QK * LOG2E));
        qa[kc] = v;
      }
    }

    uint4 kreg[4], vreg[4];
#pragma unroll
    for (int i = 0; i < 4; ++i) {
      int c = i * 256 + tid, row = c >> 4, ch = (c & 15) * 8;
      kreg[i] = *(const uint4*)(Kg + (size_t)row * 6144 + ch);
      vreg[i] = *(const uint4*)(Vg + (size_t)row * 6144 + ch);
    }

    float m_run = -INFINITY, l_run = 0.f;  // per-lane stats for q = l16
    f32x4 oacc[8] = {};
    const int qg = qt * 64 + wave * 16 + l16;

    const int nkb = qt + 1;
    for (int kb = 0; kb < nkb; ++kb) {
      // commit prefetched tile to LDS
#pragma unroll
      for (int i = 0; i < 4; ++i) {
        int c = i * 256 + tid, row = c >> 4, ch = (c & 15) * 8;
        *(uint4*)(sK + row * LK + ch) = kreg[i];
        const u16* pw = (const u16*)&vreg[i];
#pragma unroll
        for (int e = 0; e < 8; ++e) {
          int d = ch + e;
          sV[d * 64 + ((((row >> 3) ^ (d >> 3)) & 7) << 3) + (row & 7)] = pw[e];
        }
      }
      __syncthreads();
      if (kb + 1 < nkb) {
#pragma unroll
        for (int i = 0; i < 4; ++i) {
          int c = i * 256 + tid, row = c >> 4, ch = (c & 15) * 8;
          kreg[i] = *(const uint4*)(Kg + (size_t)((kb + 1) * 64 + row) * 6144 + ch);
          vreg[i] = *(const uint4*)(Vg + (size_t)((kb + 1) * 64 + row) * 6144 + ch);
        }
      }

      // S^T = K * Q^T : lane holds st[j][r] = S[k = kb*64+j*16+quad*4+r][q=l16]
      f32x4 st[4] = {};
#pragma unroll
      for (int kc = 0; kc < 4; ++kc)
#pragma unroll
        for (int j = 0; j < 4; ++j) {
          bf16x8 bb = *(const bf16x8*)(sK + (j * 16 + l16) * LK + kc * 32 + quad * 8);
          st[j] = __builtin_amdgcn_mfma_f32_16x16x32_bf16(bb, qa[kc], st[j], 0, 0, 0);
        }

      const int kg0 = kb * 64 + quad * 4;
      float mloc = NEGBIG;
#pragma unroll
      for (int j = 0; j < 4; ++j)
#pragma unroll
        for (int r = 0; r < 4; ++r) {
          float v = st[j][r];
          if (kg0 + j * 16 + r > qg) v = NEGBIG;
          st[j][r] = v;
          mloc = fmaxf(mloc, v);
        }
      mloc = fmaxf(mloc, __shfl_xor(mloc, 16, 64));
      mloc = fmaxf(mloc, __shfl_xor(mloc, 32, 64));

      // defer-max: rescale only when some row's max grew past THR=8 (log2)
      if (__any(mloc - m_run > 8.0f)) {
        float mn = fmaxf(m_run, mloc);
        float alpha = exp2f(m_run - mn);
        m_run = mn;
        l_run *= alpha;
        float ar[4];
#pragma unroll
        for (int r = 0; r < 4; ++r) ar[r] = __shfl(alpha, quad * 4 + r, 64);
#pragma unroll
        for (int dt = 0; dt < 8; ++dt)
#pragma unroll
          for (int r = 0; r < 4; ++r) oacc[dt][r] *= ar[r];
      }

      float lad = 0.f;
#pragma unroll
      for (int j = 0; j < 4; ++j)
#pragma unroll
        for (int r = 0; r < 4; ++r) {
          float p = exp2f(st[j][r] - m_run);
          st[j][r] = p;
          lad += p;
        }
      lad += __shfl_xor(lad, 16, 64);
      lad += __shfl_xor(lad, 32, 64);
      l_run += lad;

      // P^T -> sP (row q = l16, col k), then read back as PV A-frags
#pragma unroll
      for (int j = 0; j < 4; ++j)
#pragma unroll
        for (int r = 0; r < 4; ++r)
          sP[(wave * 16 + l16) * LP + j * 16 + quad * 4 + r] = f2bf(st[j][r]);
      __asm__ __volatile__("s_waitcnt lgkmcnt(0)" ::: "memory");  // sP intra-wave

#pragma unroll
      for (int kc = 0; kc < 2; ++kc) {
        bf16x8 a = *(const bf16x8*)(sP + (wave * 16 + l16) * LP + kc * 32 + quad * 8);
#pragma unroll
        for (int dt = 0; dt < 8; ++dt) {
          int d = dt * 16 + l16;
          int chk = ((kc * 4 + quad) ^ (d >> 3)) & 7;
          bf16x8 bb = *(const bf16x8*)(sV + d * 64 + chk * 8);
          oacc[dt] = __builtin_amdgcn_mfma_f32_16x16x32_bf16(a, bb, oacc[dt], 0, 0, 0);
        }
      }
      __syncthreads();
    }

    // fetch l for this lane's output rows (q = quad*4+r)
    float lfin[4];
#pragma unroll
    for (int r = 0; r < 4; ++r) lfin[r] = __shfl(l_run, quad * 4 + r, 64);

    const int srow = qt * 64 + wave * 16 + quad * 4;
#pragma unroll
    for (int dt = 0; dt < 8; ++dt)
#pragma unroll
      for (int r = 0; r < 4; ++r) {
        float val = oacc[dt][r] / lfin[r];
        O[((size_t)b * 1024 + srow + r) * 4096 + h * 128 + dt * 16 + l16] = f2bf(val);
      }
  }
}

// ---------------------------------------------------------------------------
extern "C" void kernel_launch(void* const* d_in, const int* in_sizes, int n_in,
                              void* d_out, int out_size, void* d_ws, size_t ws_size,
                              hipStream_t stream) {
  (void)in_sizes; (void)n_in; (void)out_size; (void)ws_size;
  const void* hidden = d_in[0];  // (2048, 4096)
  const void* cosb   = d_in[1];  // (2, 1024, 128)
  const void* sinb   = d_in[2];
  // d_in[3] = attention_mask (causal; reproduced analytically)
  const void* Wq = d_in[4];  // (4096, 4096)
  const void* Wk = d_in[5];  // (4096, 1024)
  const void* Wv = d_in[6];  // (4096, 1024)
  const void* Wo = d_in[7];  // (4096, 4096)

  u16* ws = (u16*)d_ws;
  u16* Wqkvt = ws;                        // bf16 (6144,4096); reused as Wot
  u16* Wot   = ws;
  u16* Xb    = ws + (size_t)25165824;     // bf16 (2048,4096); reused as attnb
  u16* attnb = Xb;
  u16* QKV   = ws + (size_t)33554432;     // bf16 (2048,6144)
  int* flags = (int*)(ws + (size_t)46137344);  // 8 ints

  // flags: 0=hidden 1=cos 2=Wq 3=Wk 4=Wv 5=Wo, 6=always-0 (bf16 out)
  detect_dtype<<<6, 64, 0, stream>>>(hidden, cosb, Wq, Wk, Wv, Wo, flags);

  // fused Wq/Wk/Wv transpose (one launch)
  transpose_qkv<<<dim3(96, 64), 256, 0, stream>>>(Wq, Wk, Wv, Wqkvt, flags);
  cast_to_bf16<<<4096, 256, 0, stream>>>(hidden, Xb, flags + 0);

  gemm_bt<<<dim3(48, 16), 256, 0, stream>>>(Xb, Wqkvt, QKV, 4096, 4096, 4096, 6144, flags + 6);
  rope_kernel<<<2560, 256, 0, stream>>>(QKV, cosb, sinb, flags + 1);

  // Wqkvt consumed by gemm1 -> overwrite with Wo^T (stream-ordered)
  transpose_to_bf16<<<dim3(64, 64), 256, 0, stream>>>(Wo, Wot, 4096, 4096, flags + 5);

  // paired q-tiles {p, 15-p}: 512 uniform blocks of 17 KV-tile iterations
  attn_kernel<<<dim3(8, 32, 2), 256, 0, stream>>>(QKV, attnb);
  // out dtype follows hidden's storage dtype
  gemm_bt<<<dim3(32, 16), 256, 0, stream>>>(attnb, Wot, d_out, 4096, 4096, 4096, 4096, flags + 0);
}